// Round 12
// baseline (555.747 us; speedup 1.0000x reference)
//
#include <hip/hip_runtime.h>

#define Bq 2
#define Nn 6
#define Dd 48
#define Hh 28
#define Ww 60
#define Cc 64
#define Xd 200
#define Yd 200
#define NP (Nn*Dd*Hh*Ww)      // 483840 points per batch
#define TOTP (Bq*NP)          // 967680 total points
#define NVOX (Xd*Yd)          // 40000 voxels per batch (Z=1)
#define NSEG (Bq*NVOX)        // 80000 segments
#define NBIN 1250             // coarse bins: 64 consecutive segments each
#define BPB  625              // bins per batch
#define VPB  64               // voxels per bin
#define CAP  512              // points staged per LDS chunk in phase_d

// Zero coarse-bin histogram (rocclr fill is pathologically slow in-graph)
__global__ __launch_bounds__(1024) void zero_bins(int* __restrict__ cnt2)
{
    int i = blockIdx.x * 1024 + threadIdx.x;
    if (i < NBIN) cnt2[i] = 0;
}

// ---------------------------------------------------------------------------
// Phase A: voxelize, rank[p] = segment id (-1 invalid), coarse-bin histogram
// ---------------------------------------------------------------------------
__global__ __launch_bounds__(256) void phase_a2(
    const float* __restrict__ geom, int* __restrict__ rank, int* __restrict__ cnt2)
{
    int p = blockIdx.x * 256 + threadIdx.x;
    if (p >= TOTP) return;
    float gx = geom[(long)p*3 + 0];
    float gy = geom[(long)p*3 + 1];
    float gz = geom[(long)p*3 + 2];
    // must match numpy astype(int32): truncate toward zero, f32 arithmetic
    int vx = (int)((gx + 50.0f) / 0.5f);
    int vy = (int)((gy + 50.0f) / 0.5f);
    int vz = (int)((gz + 10.0f) / 20.0f);
    int seg = -1;
    if (vx >= 0 && vx < Xd && vy >= 0 && vy < Yd && vz == 0) {
        int b = (p >= NP) ? 1 : 0;
        seg = b * NVOX + vx * Yd + vy;
        atomicAdd(&cnt2[seg >> 6], 1);     // coarse bin
    }
    rank[p] = seg;
}

// ---------------------------------------------------------------------------
// Scan of 1250 bin counts -> cstart[0..NBIN] (exclusive, +sentinel), ccur copy
// Single block, 1024 threads, 2 elems/thread.
// ---------------------------------------------------------------------------
__global__ __launch_bounds__(1024) void scan_bins(
    const int* __restrict__ cnt2, int* __restrict__ cstart, int* __restrict__ ccur)
{
    __shared__ int sh[1024];
    int t = threadIdx.x;
    int i0 = 2 * t, i1 = 2 * t + 1;
    int c0 = (i0 < NBIN) ? cnt2[i0] : 0;
    int c1 = (i1 < NBIN) ? cnt2[i1] : 0;
    int s = c0 + c1;
    sh[t] = s;
    __syncthreads();
    for (int off = 1; off < 1024; off <<= 1) {
        int u = (t >= off) ? sh[t - off] : 0;
        __syncthreads();
        sh[t] += u;
        __syncthreads();
    }
    int excl = sh[t] - s;
    if (i0 < NBIN) { cstart[i0] = excl;      ccur[i0] = excl; }
    if (i1 < NBIN) { cstart[i1] = excl + c0; ccur[i1] = excl + c0; }
    if (i0 == NBIN) cstart[NBIN] = excl;     // t=625: total valid count
}

// ---------------------------------------------------------------------------
// Phase C: payload scatter at COARSE granularity. Wave per 2 points:
// sequential x read (256B/point), f16 pack, append 128B row at
// ccur[bin]++ within the bin's dense region (concurrent write frontier =
// 1250 tail lines ~ 160KB reach), plus 1-byte voxel tag (seg & 63).
// ---------------------------------------------------------------------------
__global__ __launch_bounds__(256) void phase_c2(
    const int* __restrict__ rank, int* __restrict__ ccur,
    const float* __restrict__ x, unsigned int* __restrict__ perm,
    unsigned char* __restrict__ tagArr)
{
    int w    = blockIdx.x * 4 + (threadIdx.x >> 6);  // wave id (points 2w, 2w+1)
    int lane = threadIdx.x & 63;
    int half = lane >> 5;
    int li   = lane & 31;
    int p    = 2 * w + half;                         // grid exact: p < TOTP

    int seg = rank[p];
    bool valid = seg >= 0;
    int pos = 0;
    if (li == 0 && valid) pos = atomicAdd(&ccur[seg >> 6], 1);
    pos = __shfl(pos, half << 5);                    // uniform control flow

    if (valid) {
        const float2 v = *(const float2*)(x + (size_t)p * Cc + 2 * li);
        _Float16 h0 = (_Float16)v.x, h1 = (_Float16)v.y;
        unsigned int u = (unsigned int)__builtin_bit_cast(unsigned short, h0)
                       | ((unsigned int)__builtin_bit_cast(unsigned short, h1) << 16);
        perm[(size_t)pos * 32 + li] = u;             // 128B row, bin-clustered
        if (li == 0) tagArr[pos] = (unsigned char)(seg & 63);
    }
}

// ---------------------------------------------------------------------------
// Phase D: one block per bin (64 voxels). Stream the bin's dense payload
// slice SEQUENTIALLY into LDS in chunks of CAP points; counting-sort the
// chunk's 6-bit tags in LDS; accumulate per-voxel into 16 float4 register
// accumulators per lane (wave wv owns voxels wv*16..+15; 4 point-subgroups
// of 16 lanes read uint2 = 4 channels each). shfl_xor(16,32) reduce, tile
// (LDS reused from payload), coalesced out[b][c][xy] writes. No wide-reach
// random access anywhere.
// ---------------------------------------------------------------------------
__global__ __launch_bounds__(256) void phase_d2(
    const int* __restrict__ cstart, const unsigned int* __restrict__ perm,
    const unsigned char* __restrict__ tagArr, float* __restrict__ out)
{
    __shared__ unsigned int   pl[CAP * 32];      // 64 KB payload (reused as tile)
    __shared__ unsigned char  tg[CAP];
    __shared__ unsigned short ord[CAP];
    __shared__ int h[VPB], obase[VPB], off[VPB];

    int blk = blockIdx.x;                  // 0..1249
    int bb  = blk / BPB;                   // batch
    int xy0 = (blk % BPB) * VPB;
    int tid = threadIdx.x;
    int wv  = tid >> 6;                    // 0..3
    int lane = tid & 63;
    int g    = lane >> 4;                  // point subgroup 0..3
    int l15  = lane & 15;                  // channel-quad index

    int s0 = cstart[blk], s1 = cstart[blk + 1];
    int n  = s1 - s0;

    float4 A[16];
    #pragma unroll
    for (int v = 0; v < 16; ++v) A[v] = make_float4(0.f, 0.f, 0.f, 0.f);

    uint2* pl2 = (uint2*)pl;

    for (int c0 = 0; c0 < n; c0 += CAP) {
        int cn = n - c0; if (cn > CAP) cn = CAP;
        __syncthreads();                   // protect LDS reuse across chunks

        // stage tags + payload (both sequential)
        for (int i = tid; i < cn; i += 256) tg[i] = tagArr[s0 + c0 + i];
        const uint2* src = (const uint2*)(perm + (size_t)(s0 + c0) * 32);
        for (int j = tid; j < cn * 16; j += 256) pl2[j] = src[j];
        if (tid < VPB) h[tid] = 0;
        __syncthreads();

        // histogram (thread reads its own staged tg[i] indices)
        for (int i = tid; i < cn; i += 256) atomicAdd(&h[tg[i]], 1);
        __syncthreads();

        // exclusive scan of 64 counts (wave 0)
        if (tid < 64) {
            int v = h[tid];
            int inc = v;
            #pragma unroll
            for (int d = 1; d < 64; d <<= 1) {
                int u = __shfl_up(inc, d);
                if (tid >= d) inc += u;
            }
            obase[tid] = inc - v;
            off[tid]   = inc - v;
        }
        __syncthreads();

        // scatter ids into voxel-sorted ord[]
        for (int i = tid; i < cn; i += 256) {
            int ps = atomicAdd(&off[tg[i]], 1);
            ord[ps] = (unsigned short)i;
        }
        __syncthreads();

        // accumulate: wave wv owns voxels wv*16 .. wv*16+15
        #pragma unroll
        for (int v = 0; v < 16; ++v) {
            int vv = wv * 16 + v;
            int begin = obase[vv];
            int end   = begin + h[vv];
            for (int idx = begin + g; idx < end; idx += 4) {
                int i = ord[idx];
                uint2 wq = pl2[i * 16 + l15];
                A[v].x += (float)__builtin_bit_cast(_Float16, (unsigned short)(wq.x & 0xffffu));
                A[v].y += (float)__builtin_bit_cast(_Float16, (unsigned short)(wq.x >> 16));
                A[v].z += (float)__builtin_bit_cast(_Float16, (unsigned short)(wq.y & 0xffffu));
                A[v].w += (float)__builtin_bit_cast(_Float16, (unsigned short)(wq.y >> 16));
            }
        }
    }

    // cross-subgroup reduce (lanes g==0 end with channel-quad l15 finals)
    #pragma unroll
    for (int v = 0; v < 16; ++v) {
        A[v].x += __shfl_xor(A[v].x, 16); A[v].y += __shfl_xor(A[v].y, 16);
        A[v].z += __shfl_xor(A[v].z, 16); A[v].w += __shfl_xor(A[v].w, 16);
        A[v].x += __shfl_xor(A[v].x, 32); A[v].y += __shfl_xor(A[v].y, 32);
        A[v].z += __shfl_xor(A[v].z, 32); A[v].w += __shfl_xor(A[v].w, 32);
    }
    __syncthreads();                       // payload LDS free -> reuse as tile
    float* tile = (float*)pl;              // [64][68] stride-68 f32
    if (g == 0) {
        #pragma unroll
        for (int v = 0; v < 16; ++v)
            *(float4*)&tile[(wv * 16 + v) * 68 + 4 * l15] = A[v];
    }
    __syncthreads();

    // out[bb][c][xy0+xy]: s-loop writes 4 channels x 64 xy, coalesced
    float* dst = out + (long)bb * Cc * NVOX + xy0;
    int xy = tid & 63;
    int c4 = tid >> 6;                     // 0..3
    #pragma unroll
    for (int s = 0; s < 16; ++s) {
        int c = s * 4 + c4;
        dst[(long)c * NVOX + xy] = tile[xy * 68 + c];
    }
}

// ---------------------------------------------------------------------------
// Fallback (r1 atomic path) if ws is unexpectedly small
// ---------------------------------------------------------------------------
__global__ __launch_bounds__(256) void fiery_scatter_direct(
    const float* __restrict__ x, const float* __restrict__ geom,
    float* __restrict__ out)
{
    int wid  = blockIdx.x * 4 + (threadIdx.x >> 6);
    int lane = threadIdx.x & 63;
    if (wid >= TOTP) return;
    long gb = (long)wid * 3;
    float gx = geom[gb+0], gy = geom[gb+1], gz = geom[gb+2];
    int vx = (int)((gx + 50.0f) / 0.5f);
    int vy = (int)((gy + 50.0f) / 0.5f);
    int vz = (int)((gz + 10.0f) / 20.0f);
    if (!(vx >= 0 && vx < Xd && vy >= 0 && vy < Yd && vz == 0)) return;
    int b = (wid >= NP) ? 1 : 0;
    float vv = x[(long)wid * Cc + lane];
    long dst = ((long)(b * Cc + lane)) * NVOX + (vx * Yd + vy);
    atomicAdd(&out[dst], vv);
}

extern "C" void kernel_launch(void* const* d_in, const int* in_sizes, int n_in,
                              void* d_out, int out_size, void* d_ws, size_t ws_size,
                              hipStream_t stream)
{
    const float* x    = (const float*)d_in[0];
    const float* geom = (const float*)d_in[1];
    float* out = (float*)d_out;

    // ws layout: perm[TOTP*32 u32] | rank[TOTP] | cnt2[NBIN] | cstart[NBIN+1]
    //          | ccur[NBIN] | tagArr[TOTP u8]
    size_t need = (size_t)TOTP * 32 * 4 + (size_t)TOTP * 4
                + (size_t)(NBIN * 3 + 1) * 4 + (size_t)TOTP;
    if (ws_size >= need) {
        unsigned int* perm = (unsigned int*)d_ws;
        int* rank   = (int*)(perm + (size_t)TOTP * 32);
        int* cnt2   = rank + TOTP;
        int* cstart = cnt2 + NBIN;
        int* ccur   = cstart + NBIN + 1;
        unsigned char* tagArr = (unsigned char*)(ccur + NBIN);

        zero_bins<<<2, 1024, 0, stream>>>(cnt2);
        phase_a2<<<TOTP/256, 256, 0, stream>>>(geom, rank, cnt2);
        scan_bins<<<1, 1024, 0, stream>>>(cnt2, cstart, ccur);
        phase_c2<<<TOTP/8, 256, 0, stream>>>(rank, ccur, x, perm, tagArr);
        phase_d2<<<NBIN, 256, 0, stream>>>(cstart, perm, tagArr, out);
    } else {
        hipMemsetAsync(out, 0, (size_t)out_size * sizeof(float), stream);
        fiery_scatter_direct<<<TOTP/4, 256, 0, stream>>>(x, geom, out);
    }
}

// Round 13
// 137.201 us; speedup vs baseline: 4.0506x; 4.0506x over previous
//
#include <hip/hip_runtime.h>

#define Bq 2
#define Nn 6
#define Dd 48
#define Hh 28
#define Ww 60
#define Cc 64
#define Xd 200
#define Yd 200
#define NP (Nn*Dd*Hh*Ww)      // 483840 points per batch
#define TOTP (Bq*NP)          // 967680 total points
#define NVOX (Xd*Yd)          // 40000 voxels per batch (Z=1)
#define NSEG (Bq*NVOX)        // 80000 segments
#define NB1  79               // ceil(NSEG/1024)
#define CAP  256              // staged point-ids per wave (avg need ~66)

typedef float f32x4 __attribute__((ext_vector_type(4)));

// Zero the histogram ourselves: rocclr fillBufferAligned is pathologically slow
__global__ __launch_bounds__(1024) void zero_cnt(int* __restrict__ cnt)
{
    int i = blockIdx.x * 1024 + threadIdx.x;
    if (i < NSEG) cnt[i] = 0;
}

// ---------------------------------------------------------------------------
// Phase A: voxelize each point, store segment id (-1 invalid), histogram count
// ---------------------------------------------------------------------------
__global__ __launch_bounds__(256) void phase_a(
    const float* __restrict__ geom, int* __restrict__ rank, int* __restrict__ cnt)
{
    int p = blockIdx.x * 256 + threadIdx.x;
    if (p >= TOTP) return;
    float gx = geom[(long)p*3 + 0];
    float gy = geom[(long)p*3 + 1];
    float gz = geom[(long)p*3 + 2];
    // must match numpy astype(int32): truncate toward zero, f32 arithmetic
    int vx = (int)((gx + 50.0f) / 0.5f);
    int vy = (int)((gy + 50.0f) / 0.5f);
    int vz = (int)((gz + 10.0f) / 20.0f);
    int seg = -1;
    if (vx >= 0 && vx < Xd && vy >= 0 && vy < Yd && vz == 0) {
        int b = (p >= NP) ? 1 : 0;
        seg = b * NVOX + vx * Yd + vy;
        atomicAdd(&cnt[seg], 1);
    }
    rank[p] = seg;
}

// Scan P1: per-1024-block exclusive scan of cnt -> start, block totals -> bsum
__global__ __launch_bounds__(1024) void scan_p1(
    const int* __restrict__ cnt, int* __restrict__ start, int* __restrict__ bsum)
{
    __shared__ int sh[1024];
    int tid = threadIdx.x;
    int i = blockIdx.x * 1024 + tid;
    int v = (i < NSEG) ? cnt[i] : 0;
    sh[tid] = v;
    __syncthreads();
    for (int off = 1; off < 1024; off <<= 1) {
        int t = (tid >= off) ? sh[tid - off] : 0;
        __syncthreads();
        sh[tid] += t;
        __syncthreads();
    }
    if (i < NSEG) start[i] = sh[tid] - v;
    if (tid == 1023) bsum[blockIdx.x] = sh[1023];
}

// Scan P2: exclusive scan of block totals (single block)
__global__ __launch_bounds__(128) void scan_p2(int* __restrict__ bsum)
{
    __shared__ int sh[128];
    int tid = threadIdx.x;
    int v = (tid < NB1) ? bsum[tid] : 0;
    sh[tid] = v;
    __syncthreads();
    for (int off = 1; off < 128; off <<= 1) {
        int t = (tid >= off) ? sh[tid - off] : 0;
        __syncthreads();
        sh[tid] += t;
        __syncthreads();
    }
    if (tid < NB1) bsum[tid] = sh[tid] - v;
}

// Scan P3: add block offsets
__global__ __launch_bounds__(1024) void scan_p3(
    int* __restrict__ start, const int* __restrict__ bsum)
{
    int i = blockIdx.x * 1024 + threadIdx.x;
    if (i < NSEG) start[i] += bsum[blockIdx.x];
}

// Phase C: scatter point ids into segment-ordered list; start[] becomes end[]
__global__ __launch_bounds__(256) void phase_c(
    const int* __restrict__ rank, int* __restrict__ start, int* __restrict__ order)
{
    int p = blockIdx.x * 256 + threadIdx.x;
    if (p >= TOTP) return;
    int seg = rank[p];
    if (seg < 0) return;
    int pos = atomicAdd(&start[seg], 1);
    order[pos] = p;
}

// ---------------------------------------------------------------------------
// Phase D: 128-thread blocks, 2 waves, 8 voxels per wave -> grid 5000 (2x
// finer tail granularity than 256-thread version; 16 blocks/CU x 2 waves
// = full 32 waves/CU). Proven R6 inner loop: stage the wave's contiguous
// order[] slice in LDS, per-voxel 2-wide-unrolled float4 gather (16 lanes x
// float4 per point, 4 point-subgroups), shfl_xor(16,32) reduce, tiny LDS
// transpose tile, NONTEMPORAL out stores (don't evict gather-hot x from
// L2/L3). No atomics.
// ---------------------------------------------------------------------------
__global__ __launch_bounds__(128) void phase_d(
    const int* __restrict__ endp, const int* __restrict__ order,
    const float* __restrict__ x, float* __restrict__ out)
{
    __shared__ int   ord_sh[2][CAP];
    __shared__ float tile[16][68];
    int blk  = blockIdx.x;                 // 0 .. 4999
    int b    = blk / (NVOX/16);            // 2500 blocks per batch
    int xy0  = (blk % (NVOX/16)) * 16;
    int wv   = threadIdx.x >> 6;           // 0..1
    int lane = threadIdx.x & 63;
    int seg0 = b * NVOX + xy0 + wv * 8;    // this wave's first voxel

    // lane j<9 loads boundary end[seg0-1+j]; e[v]=begin of voxel v, e[v+1]=end
    int e = 0;
    if (lane < 9) {
        int idx = seg0 - 1 + lane;
        e = (idx >= 0) ? endp[idx] : 0;
    }
    int eb0 = __shfl(e, 0);
    int rb[9];
    #pragma unroll
    for (int j = 0; j < 9; ++j) rb[j] = __shfl(e, j) - eb0;
    int count = rb[8];

    int g = lane >> 4;                     // point subgroup 0..3
    int q = (lane & 15) * 4;               // channel base for this lane

    float4 A[8];
    #pragma unroll
    for (int v = 0; v < 8; ++v) A[v] = make_float4(0.f, 0.f, 0.f, 0.f);

    if (count <= CAP) {                    // ~always (avg 66, CAP=256 ~20+sigma)
        for (int i = lane; i < count; i += 64)
            ord_sh[wv][i] = order[eb0 + i];
        #pragma unroll
        for (int v = 0; v < 8; ++v) {
            int re = rb[v + 1];
            int t  = rb[v] + g;
            for (; t + 4 < re; t += 8) {   // 2 points per chain step
                int p0 = ord_sh[wv][t];
                int p1 = ord_sh[wv][t + 4];
                const float4 a0 = *(const float4*)(x + (long)p0 * Cc + q);
                const float4 a1 = *(const float4*)(x + (long)p1 * Cc + q);
                A[v].x += a0.x + a1.x; A[v].y += a0.y + a1.y;
                A[v].z += a0.z + a1.z; A[v].w += a0.w + a1.w;
            }
            if (t < re) {
                int p0 = ord_sh[wv][t];
                const float4 a0 = *(const float4*)(x + (long)p0 * Cc + q);
                A[v].x += a0.x; A[v].y += a0.y; A[v].z += a0.z; A[v].w += a0.w;
            }
        }
    } else {                               // fallback: direct global order[]
        #pragma unroll
        for (int v = 0; v < 8; ++v) {
            int begin = eb0 + rb[v];
            int endv  = eb0 + rb[v + 1];
            for (int t = begin + g; t < endv; t += 4) {
                int p0 = order[t];
                const float4 a0 = *(const float4*)(x + (long)p0 * Cc + q);
                A[v].x += a0.x; A[v].y += a0.y; A[v].z += a0.z; A[v].w += a0.w;
            }
        }
    }

    // cross-subgroup reduce; lanes g==0 hold finals for channels q..q+3
    #pragma unroll
    for (int v = 0; v < 8; ++v) {
        A[v].x += __shfl_xor(A[v].x, 16); A[v].y += __shfl_xor(A[v].y, 16);
        A[v].z += __shfl_xor(A[v].z, 16); A[v].w += __shfl_xor(A[v].w, 16);
        A[v].x += __shfl_xor(A[v].x, 32); A[v].y += __shfl_xor(A[v].y, 32);
        A[v].z += __shfl_xor(A[v].z, 32); A[v].w += __shfl_xor(A[v].w, 32);
    }
    if (g == 0) {
        #pragma unroll
        for (int v = 0; v < 8; ++v)
            *(float4*)&tile[wv*8 + v][q] = A[v];
    }
    __syncthreads();

    // out[b][c][xy0 + hv*8 .. +8]: lane c, half hv -> two NT float4 stores
    int c  = threadIdx.x & 63;
    int hv = threadIdx.x >> 6;             // 0..1 -> voxel rows hv*8..hv*8+7
    float4 w0 = make_float4(tile[hv*8+0][c], tile[hv*8+1][c],
                            tile[hv*8+2][c], tile[hv*8+3][c]);
    float4 w1 = make_float4(tile[hv*8+4][c], tile[hv*8+5][c],
                            tile[hv*8+6][c], tile[hv*8+7][c]);
    float* dst = out + (long)b * Cc * NVOX + (long)c * NVOX + xy0 + hv*8;
    __builtin_nontemporal_store(*(f32x4*)&w0, (f32x4*)dst);
    __builtin_nontemporal_store(*(f32x4*)&w1, (f32x4*)(dst + 4));
}

// ---------------------------------------------------------------------------
// Fallback (r1 atomic path) if ws is unexpectedly small
// ---------------------------------------------------------------------------
__global__ __launch_bounds__(256) void fiery_scatter_direct(
    const float* __restrict__ x, const float* __restrict__ geom,
    float* __restrict__ out)
{
    int wid  = blockIdx.x * 4 + (threadIdx.x >> 6);
    int lane = threadIdx.x & 63;
    if (wid >= TOTP) return;
    long gb = (long)wid * 3;
    float gx = geom[gb+0], gy = geom[gb+1], gz = geom[gb+2];
    int vx = (int)((gx + 50.0f) / 0.5f);
    int vy = (int)((gy + 50.0f) / 0.5f);
    int vz = (int)((gz + 10.0f) / 20.0f);
    if (!(vx >= 0 && vx < Xd && vy >= 0 && vy < Yd && vz == 0)) return;
    int b = (wid >= NP) ? 1 : 0;
    float vv = x[(long)wid * Cc + lane];
    long dst = ((long)(b * Cc + lane)) * NVOX + (vx * Yd + vy);
    atomicAdd(&out[dst], vv);
}

extern "C" void kernel_launch(void* const* d_in, const int* in_sizes, int n_in,
                              void* d_out, int out_size, void* d_ws, size_t ws_size,
                              hipStream_t stream)
{
    const float* x    = (const float*)d_in[0];
    const float* geom = (const float*)d_in[1];
    float* out = (float*)d_out;

    // ws layout: rank[TOTP] | order[TOTP] | cnt[NSEG] | start[NSEG] | bsum[128]
    size_t need = ((size_t)TOTP * 2 + (size_t)NSEG * 2 + 128) * sizeof(int);
    if (ws_size >= need) {
        int* rank  = (int*)d_ws;
        int* order = rank  + TOTP;
        int* cnt   = order + TOTP;
        int* start = cnt   + NSEG;
        int* bsum  = start + NSEG;

        zero_cnt<<<NB1, 1024, 0, stream>>>(cnt);
        phase_a<<<TOTP/256, 256, 0, stream>>>(geom, rank, cnt);
        scan_p1<<<NB1, 1024, 0, stream>>>(cnt, start, bsum);
        scan_p2<<<1, 128, 0, stream>>>(bsum);
        scan_p3<<<NB1, 1024, 0, stream>>>(start, bsum);
        phase_c<<<TOTP/256, 256, 0, stream>>>(rank, start, order);
        phase_d<<<Bq*(NVOX/16), 128, 0, stream>>>(start, order, x, out);
    } else {
        hipMemsetAsync(out, 0, (size_t)out_size * sizeof(float), stream);
        fiery_scatter_direct<<<TOTP/4, 256, 0, stream>>>(x, geom, out);
    }
}